// Round 12
// baseline (1215.739 us; speedup 1.0000x reference)
//
#include <hip/hip_runtime.h>

#define DDIM 256
#define HDIM 512
#define NWF (2 * DDIM + 2)      // 514 Wfused/bvec blocks
#define NWEIGHT (NWF + DDIM)    // +256 W2T blocks = 770

typedef float f32x4 __attribute__((ext_vector_type(4)));
typedef short bf16x8 __attribute__((ext_vector_type(8)));

__device__ inline unsigned short f2bf(float f) {
  unsigned int u = __float_as_uint(f);
  u += 0x7fff + ((u >> 16) & 1);  // round-to-nearest-even
  return (unsigned short)(u >> 16);
}

// ---------------------------------------------------------------------------
// Mega kernel: weights + segsum + slab-MLP in ONE dispatch.
//   blocks [0,514):        WfT[j][i] = (W_in@W1)[i][j] bf16; bvec = b_in@W1;
//                          publish flags[b]=1 (release)
//   blocks [514,770):      W2T[n][k] = W2[k][n] bf16; publish flags[b]=1
//   blocks [770,770+G):    segment g: binary-search rows, stream+sum x,
//                          store Sb[g] bf16 + counts[g]; atomicAdd slab
//                          counter; the 16th arriver runs the slab's MLP:
//                          out[16 rows] = relu(Sb@Wf + cnt*bvec + b1)@W2 + b2
// flags/scount zeroed by hipMemsetAsync each call (poison/order-proof).
// ---------------------------------------------------------------------------
__global__ __launch_bounds__(256) void mega_kernel(
    const float* __restrict__ x, const int* __restrict__ batch,
    const float* __restrict__ W_in, const float* __restrict__ b_in,
    const float* __restrict__ W1, const float* __restrict__ W2,
    const float* __restrict__ b1, const float* __restrict__ b2,
    unsigned short* __restrict__ WfT, unsigned short* __restrict__ W2T,
    float* __restrict__ bvec, unsigned short* __restrict__ Sb,
    float* __restrict__ counts, unsigned int* __restrict__ flags,
    unsigned int* __restrict__ scount, float* __restrict__ out, int N,
    int G) {
  __shared__ __align__(128) char pool[16 * 1024];
  const int b = blockIdx.x;
  const int tid = threadIdx.x;

  if (b < NWF) {  // Wfused^T (bf16) and bvec
    float* vrow = (float*)pool;
    const bool is_b = (b >= 2 * DDIM);
    const int i = is_b ? 0 : (b >> 1);
    const int half = is_b ? (b - 2 * DDIM) : (b & 1);
    const float* src = is_b ? b_in : (W_in + (size_t)i * DDIM);
    vrow[tid] = src[tid];
    __syncthreads();
    const int j = half * 256 + tid;
    float h = 0.f;
#pragma unroll 8
    for (int k = 0; k < DDIM; ++k) h += vrow[k] * W1[(size_t)k * HDIM + j];
    if (is_b) bvec[j] = h;
    else WfT[(size_t)j * DDIM + i] = f2bf(h);
    __syncthreads();
    if (tid == 0) {
      __threadfence();
      __hip_atomic_store(&flags[b], 1u, __ATOMIC_RELEASE,
                         __HIP_MEMORY_SCOPE_AGENT);
    }
    return;
  }
  if (b < NWEIGHT) {  // W2^T (bf16)
    const int n = b - NWF;
    for (int k = tid; k < HDIM; k += 256)
      W2T[(size_t)n * HDIM + k] = f2bf(W2[(size_t)k * DDIM + n]);
    __syncthreads();
    if (tid == 0) {
      __threadfence();
      __hip_atomic_store(&flags[b], 1u, __ATOMIC_RELEASE,
                         __HIP_MEMORY_SCOPE_AGENT);
    }
    return;
  }

  // ---- segment-sum ----
  const int g = b - NWEIGHT;
  float(*red)[DDIM] = (float(*)[DDIM])pool;         // 3 KB
  int* se = (int*)(pool + 3 * DDIM * 4);            // 8 B
  int* doMLP = (int*)(pool + 3 * DDIM * 4 + 8);

  if (tid < 2) {  // lower_bound(batch, g) and (g+1)
    const int target = g + tid;
    int lo = 0, hi = N;
    while (lo < hi) {
      const int mid = (lo + hi) >> 1;
      if (batch[mid] < target) lo = mid + 1;
      else hi = mid;
    }
    se[tid] = lo;
  }
  __syncthreads();
  const int start = se[0], end = se[1];

  const int w  = tid >> 6;
  const int c4 = (tid & 63) << 2;
  const float* xp = x + c4;

  f32x4 a0 = {0.f, 0.f, 0.f, 0.f};
  f32x4 a1 = {0.f, 0.f, 0.f, 0.f};
  f32x4 a2 = {0.f, 0.f, 0.f, 0.f};
  f32x4 a3 = {0.f, 0.f, 0.f, 0.f};

  int i = start + w;
  for (; i + 12 < end; i += 16) {
    const f32x4 v0 = __builtin_nontemporal_load(
        reinterpret_cast<const f32x4*>(xp + (size_t)i * DDIM));
    const f32x4 v1 = __builtin_nontemporal_load(
        reinterpret_cast<const f32x4*>(xp + (size_t)(i + 4) * DDIM));
    const f32x4 v2 = __builtin_nontemporal_load(
        reinterpret_cast<const f32x4*>(xp + (size_t)(i + 8) * DDIM));
    const f32x4 v3 = __builtin_nontemporal_load(
        reinterpret_cast<const f32x4*>(xp + (size_t)(i + 12) * DDIM));
    a0 += v0;
    a1 += v1;
    a2 += v2;
    a3 += v3;
  }
  for (; i < end; i += 4) {
    const f32x4 v0 = __builtin_nontemporal_load(
        reinterpret_cast<const f32x4*>(xp + (size_t)i * DDIM));
    a0 += v0;
  }
  a0 += a1;
  a2 += a3;
  a0 += a2;

  if (w != 0) *reinterpret_cast<f32x4*>(&red[w - 1][c4]) = a0;
  __syncthreads();
  if (w == 0) {
#pragma unroll
    for (int r = 0; r < 3; ++r) a0 += *reinterpret_cast<const f32x4*>(&red[r][c4]);
    ushort4 sv;
    sv.x = f2bf(a0.x);
    sv.y = f2bf(a0.y);
    sv.z = f2bf(a0.z);
    sv.w = f2bf(a0.w);
    *reinterpret_cast<ushort4*>(Sb + (size_t)g * DDIM + c4) = sv;
    if (tid == 0) counts[g] = (float)(end - start);
  }
  __syncthreads();
  if (tid == 0) {  // publish this segment; 16th arriver runs the slab MLP
    __threadfence();
    const unsigned old = __hip_atomic_fetch_add(
        &scount[g >> 4], 1u, __ATOMIC_ACQ_REL, __HIP_MEMORY_SCOPE_AGENT);
    *doMLP = (old == 15u);
  }
  __syncthreads();
  if (!*doMLP) return;

  // ---- slab MLP (last arriver), rows [16s, 16s+16) ----
  // Wait for weight publication (long done in practice; order-independent).
  for (int f = tid; f < NWEIGHT; f += 256)
    while (__hip_atomic_load(&flags[f], __ATOMIC_ACQUIRE,
                             __HIP_MEMORY_SCOPE_AGENT) != 1u)
      __builtin_amdgcn_s_sleep(2);
  __threadfence();
  __syncthreads();

  const int s = g >> 4;
  const int m0 = s * 16;
  const int wid = tid >> 6, lane = tid & 63;
  const int l15 = lane & 15, lk8 = (lane >> 4) << 3;
  const int rbase = (lane >> 4) << 2;
  char* hsb = pool;  // 16 KB swizzled H slab (red/se dead after syncthreads)

  // Phase 1: H[16][512] = relu(Sb@Wf + cnt*bvec + b1) -> LDS bf16 swizzled
  {
    const unsigned short* Ap = Sb + (size_t)(m0 + l15) * DDIM + lk8;
    const unsigned short* Bp = WfT + (size_t)(wid * 128 + l15) * DDIM + lk8;
    f32x4 acc[8] = {};
#pragma unroll
    for (int k0 = 0; k0 < DDIM; k0 += 32) {
      const bf16x8 a = *reinterpret_cast<const bf16x8*>(Ap + k0);
#pragma unroll
      for (int sj = 0; sj < 8; ++sj) {
        const bf16x8 bb =
            *reinterpret_cast<const bf16x8*>(Bp + (size_t)sj * 16 * DDIM + k0);
        acc[sj] =
            __builtin_amdgcn_mfma_f32_16x16x32_bf16(a, bb, acc[sj], 0, 0, 0);
      }
    }
#pragma unroll
    for (int sj = 0; sj < 8; ++sj) {
      const int col = wid * 128 + sj * 16 + l15;
      const float vj = bvec[col];
      const float bj = b1[col];
#pragma unroll
      for (int r = 0; r < 4; ++r) {
        const int row = rbase + r;
        float v = acc[sj][r] + counts[m0 + row] * vj + bj;
        v = fmaxf(v, 0.f);
        const int byte = (row << 10) + (col << 1);
        *(unsigned short*)(hsb + (byte ^ ((row & 7) << 4))) = f2bf(v);
      }
    }
  }
  __syncthreads();

  // Phase 2: out[16][256] = H @ W2 + b2
  {
    const unsigned short* B2p = W2T + (size_t)(wid * 64 + l15) * HDIM + lk8;
    f32x4 acc2[4] = {};
#pragma unroll
    for (int k0 = 0; k0 < HDIM; k0 += 32) {
      const int kb = (l15 << 10) + ((lk8 + k0) << 1);
      const bf16x8 a =
          *reinterpret_cast<const bf16x8*>(hsb + (kb ^ ((l15 & 7) << 4)));
#pragma unroll
      for (int sj = 0; sj < 4; ++sj) {
        const bf16x8 bb =
            *reinterpret_cast<const bf16x8*>(B2p + (size_t)sj * 16 * HDIM + k0);
        acc2[sj] =
            __builtin_amdgcn_mfma_f32_16x16x32_bf16(a, bb, acc2[sj], 0, 0, 0);
      }
    }
#pragma unroll
    for (int sj = 0; sj < 4; ++sj) {
      const int col = wid * 64 + sj * 16 + l15;
      const float bj = b2[col];
#pragma unroll
      for (int r = 0; r < 4; ++r) {
        const int row = m0 + rbase + r;
        out[(size_t)row * DDIM + col] = acc2[sj][r] + bj;
      }
    }
  }
}

extern "C" void kernel_launch(void* const* d_in, const int* in_sizes, int n_in,
                              void* d_out, int out_size, void* d_ws,
                              size_t ws_size, hipStream_t stream) {
  const float* x     = (const float*)d_in[0];
  const int*   batch = (const int*)d_in[1];
  const float* W_in  = (const float*)d_in[2];
  const float* b_in  = (const float*)d_in[3];
  const float* W1    = (const float*)d_in[4];
  const float* b1    = (const float*)d_in[5];
  const float* W2    = (const float*)d_in[6];
  const float* b2    = (const float*)d_in[7];
  float* out = (float*)d_out;

  const int N = in_sizes[1];       // 1,000,000 rows
  const int G = out_size / DDIM;   // 4096 segments

  // Workspace layout:
  char* wsb = (char*)d_ws;
  size_t off = 0;
  unsigned short* WfT = (unsigned short*)(wsb + off);  off += (size_t)HDIM * DDIM * 2;
  unsigned short* W2T = (unsigned short*)(wsb + off);  off += (size_t)DDIM * HDIM * 2;
  float* bvec   = (float*)(wsb + off);                 off += (size_t)HDIM * 4;
  float* counts = (float*)(wsb + off);                 off += (size_t)G * 4;
  unsigned short* Sb = (unsigned short*)(wsb + off);   off += (size_t)G * DDIM * 2;
  unsigned int* flags  = (unsigned int*)(wsb + off);   off += (size_t)NWEIGHT * 4;
  unsigned int* scount = (unsigned int*)(wsb + off);

  // Zero flags + slab counters (contiguous) — poison/order-proof, per call.
  hipMemsetAsync(flags, 0, (NWEIGHT + G / 16) * sizeof(unsigned int), stream);

  // One dispatch: weights + segsum + slab-MLP (last arriver).
  mega_kernel<<<NWEIGHT + G, 256, 0, stream>>>(
      x, batch, W_in, b_in, W1, W2, b1, b2, WfT, W2T, bvec, Sb, counts, flags,
      scount, out, N, G);
}

// Round 13
// 209.851 us; speedup vs baseline: 5.7933x; 5.7933x over previous
//
#include <hip/hip_runtime.h>

#define DDIM 256
#define HDIM 512

typedef float f32x4 __attribute__((ext_vector_type(4)));
typedef short bf16x8 __attribute__((ext_vector_type(8)));

__device__ inline unsigned short f2bf(float f) {
  unsigned int u = __float_as_uint(f);
  u += 0x7fff + ((u >> 16) & 1);  // round-to-nearest-even
  return (unsigned short)(u >> 16);
}

// ---------------------------------------------------------------------------
// Fused main kernel. Weight-transform blocks FIRST so they overlap the
// HBM-bound segment stream:
//   blocks [0,514):      WfT[j][i] = (W_in@W1)[i][j] bf16; bvec = b_in@W1
//   blocks [514,770):    W2T[n][k] = W2[k][n] bf16
//   blocks [770,770+G):  segment g: binary-search rows, stream+sum x,
//                        store Sb[g] bf16 + counts[g]
// Plain (cacheable) x loads: no reuse within a pass, but the 256 MB L3 can
// retain part of x across graph replays; NT bits would forfeit that.
// ---------------------------------------------------------------------------
__global__ __launch_bounds__(256) void fused_main_kernel(
    const float* __restrict__ x, const int* __restrict__ batch,
    const float* __restrict__ W_in, const float* __restrict__ b_in,
    const float* __restrict__ W1, const float* __restrict__ W2,
    unsigned short* __restrict__ WfT, unsigned short* __restrict__ W2T,
    float* __restrict__ bvec, unsigned short* __restrict__ Sb,
    float* __restrict__ counts, int N, int G) {
  const int b = blockIdx.x;

  if (b < 2 * DDIM + 2) {  // Wfused^T (bf16) and bvec
    __shared__ float vrow[DDIM];
    const bool is_b = (b >= 2 * DDIM);
    const int i = is_b ? 0 : (b >> 1);
    const int half = is_b ? (b - 2 * DDIM) : (b & 1);
    const float* src = is_b ? b_in : (W_in + (size_t)i * DDIM);
    vrow[threadIdx.x] = src[threadIdx.x];
    __syncthreads();

    const int j = half * 256 + threadIdx.x;
    float h = 0.f;
#pragma unroll 8
    for (int k = 0; k < DDIM; ++k) h += vrow[k] * W1[(size_t)k * HDIM + j];
    if (is_b) bvec[j] = h;
    else WfT[(size_t)j * DDIM + i] = f2bf(h);  // [N=512][K=256]
    return;
  }
  if (b < 2 * DDIM + 2 + DDIM) {  // W2^T (bf16)
    const int n = b - (2 * DDIM + 2);  // [N=256][K=512]
    for (int k = threadIdx.x; k < HDIM; k += 256)
      W2T[(size_t)n * HDIM + k] = f2bf(W2[(size_t)k * DDIM + n]);
    return;
  }

  // ---- segment-sum block ----
  const int g = b - (2 * DDIM + 2 + DDIM);
  __shared__ int se[2];
  __shared__ float red[3][DDIM];

  if (threadIdx.x < 2) {  // lower_bound(batch, g) and (g+1)
    const int target = g + threadIdx.x;
    int lo = 0, hi = N;
    while (lo < hi) {
      const int mid = (lo + hi) >> 1;
      if (batch[mid] < target) lo = mid + 1;
      else hi = mid;
    }
    se[threadIdx.x] = lo;
  }
  __syncthreads();
  const int start = se[0], end = se[1];

  const int w  = threadIdx.x >> 6;          // wave 0..3
  const int c4 = (threadIdx.x & 63) << 2;   // column base
  const float* xp = x + c4;

  f32x4 a0 = {0.f, 0.f, 0.f, 0.f};
  f32x4 a1 = {0.f, 0.f, 0.f, 0.f};
  f32x4 a2 = {0.f, 0.f, 0.f, 0.f};
  f32x4 a3 = {0.f, 0.f, 0.f, 0.f};

  int i = start + w;
  for (; i + 12 < end; i += 16) {
    const f32x4 v0 = *reinterpret_cast<const f32x4*>(xp + (size_t)i * DDIM);
    const f32x4 v1 =
        *reinterpret_cast<const f32x4*>(xp + (size_t)(i + 4) * DDIM);
    const f32x4 v2 =
        *reinterpret_cast<const f32x4*>(xp + (size_t)(i + 8) * DDIM);
    const f32x4 v3 =
        *reinterpret_cast<const f32x4*>(xp + (size_t)(i + 12) * DDIM);
    a0 += v0;
    a1 += v1;
    a2 += v2;
    a3 += v3;
  }
  for (; i < end; i += 4) {
    a0 += *reinterpret_cast<const f32x4*>(xp + (size_t)i * DDIM);
  }
  a0 += a1;
  a2 += a3;
  a0 += a2;

  if (w != 0) *reinterpret_cast<f32x4*>(&red[w - 1][c4]) = a0;
  __syncthreads();
  if (w == 0) {
#pragma unroll
    for (int r = 0; r < 3; ++r) {
      a0 += *reinterpret_cast<const f32x4*>(&red[r][c4]);
    }
    ushort4 sv;
    sv.x = f2bf(a0.x);
    sv.y = f2bf(a0.y);
    sv.z = f2bf(a0.z);
    sv.w = f2bf(a0.w);
    *reinterpret_cast<ushort4*>(Sb + (size_t)g * DDIM + c4) = sv;
    if (threadIdx.x == 0) counts[g] = (float)(end - start);
  }
}

// ---------------------------------------------------------------------------
// Fused MLP: one block per 16-row slab. Phase 1: H = relu(Sb@Wf + cnt*bvec
// + b1) -> LDS as bf16 (XOR-swizzled both sides). Phase 2: out = H @ W2 + b2
// from LDS. MFMA fragment idiom as verified in R8: A row=lane&15, B col=
// lane&15, k=(lane>>4)*8+e; D col=lane&15, row=(lane>>4)*4+reg.
// ---------------------------------------------------------------------------
__global__ __launch_bounds__(256) void mlp_kernel(
    const unsigned short* __restrict__ Sb,
    const unsigned short* __restrict__ WfT,
    const unsigned short* __restrict__ W2T, const float* __restrict__ bvec,
    const float* __restrict__ b1, const float* __restrict__ b2,
    const float* __restrict__ counts, float* __restrict__ out) {
  __shared__ unsigned short Hs[16 * HDIM];  // 16 KB, swizzled layout
  const int tid = threadIdx.x;
  const int wid = tid >> 6, lane = tid & 63;
  const int l15 = lane & 15, lk8 = (lane >> 4) << 3;
  const int rbase = (lane >> 4) << 2;
  const int m0 = blockIdx.x * 16;

  // ---- Phase 1: H slab [16][512] ----
  const unsigned short* Ap = Sb + (size_t)(m0 + l15) * DDIM + lk8;
  const unsigned short* Bp = WfT + (size_t)(wid * 128 + l15) * DDIM + lk8;

  f32x4 acc[8] = {};
#pragma unroll
  for (int k0 = 0; k0 < DDIM; k0 += 32) {
    const bf16x8 a = *reinterpret_cast<const bf16x8*>(Ap + k0);
#pragma unroll
    for (int sj = 0; sj < 8; ++sj) {
      const bf16x8 bb =
          *reinterpret_cast<const bf16x8*>(Bp + (size_t)sj * 16 * DDIM + k0);
      acc[sj] = __builtin_amdgcn_mfma_f32_16x16x32_bf16(a, bb, acc[sj], 0, 0, 0);
    }
  }
  // epilogue -> LDS (swizzled bf16)
  char* hsb = (char*)Hs;
#pragma unroll
  for (int sj = 0; sj < 8; ++sj) {
    const int col = wid * 128 + sj * 16 + l15;
    const float vj = bvec[col];
    const float bj = b1[col];
#pragma unroll
    for (int r = 0; r < 4; ++r) {
      const int row = rbase + r;
      float v = acc[sj][r] + counts[m0 + row] * vj + bj;
      v = fmaxf(v, 0.f);
      const int byte = (row << 10) + (col << 1);
      *(unsigned short*)(hsb + (byte ^ ((row & 7) << 4))) = f2bf(v);
    }
  }
  __syncthreads();

  // ---- Phase 2: out slab [16][256] ----
  const unsigned short* B2p = W2T + (size_t)(wid * 64 + l15) * HDIM + lk8;
  f32x4 acc2[4] = {};
#pragma unroll
  for (int k0 = 0; k0 < HDIM; k0 += 32) {
    const int kb = (l15 << 10) + ((lk8 + k0) << 1);
    const bf16x8 a =
        *reinterpret_cast<const bf16x8*>(hsb + (kb ^ ((l15 & 7) << 4)));
#pragma unroll
    for (int sj = 0; sj < 4; ++sj) {
      const bf16x8 bb =
          *reinterpret_cast<const bf16x8*>(B2p + (size_t)sj * 16 * HDIM + k0);
      acc2[sj] = __builtin_amdgcn_mfma_f32_16x16x32_bf16(a, bb, acc2[sj], 0, 0, 0);
    }
  }
#pragma unroll
  for (int sj = 0; sj < 4; ++sj) {
    const int col = wid * 64 + sj * 16 + l15;
    const float bj = b2[col];
#pragma unroll
    for (int r = 0; r < 4; ++r) {
      const int row = m0 + rbase + r;
      out[(size_t)row * DDIM + col] = acc2[sj][r] + bj;
    }
  }
}

extern "C" void kernel_launch(void* const* d_in, const int* in_sizes, int n_in,
                              void* d_out, int out_size, void* d_ws,
                              size_t ws_size, hipStream_t stream) {
  const float* x     = (const float*)d_in[0];
  const int*   batch = (const int*)d_in[1];
  const float* W_in  = (const float*)d_in[2];
  const float* b_in  = (const float*)d_in[3];
  const float* W1    = (const float*)d_in[4];
  const float* b1    = (const float*)d_in[5];
  const float* W2    = (const float*)d_in[6];
  const float* b2    = (const float*)d_in[7];
  float* out = (float*)d_out;

  const int N = in_sizes[1];       // 1,000,000 rows
  const int G = out_size / DDIM;   // 4096 segments

  // Workspace layout (regions naturally aligned):
  char* wsb = (char*)d_ws;
  size_t off = 0;
  unsigned short* WfT = (unsigned short*)(wsb + off);  off += (size_t)HDIM * DDIM * 2;
  unsigned short* W2T = (unsigned short*)(wsb + off);  off += (size_t)DDIM * HDIM * 2;
  float* bvec   = (float*)(wsb + off);                 off += (size_t)HDIM * 4;
  float* counts = (float*)(wsb + off);                 off += (size_t)G * 4;
  unsigned short* Sb = (unsigned short*)(wsb + off);

  // 1) Weight transforms (first blocks, overlap the segment stream) + segsum
  fused_main_kernel<<<2 * DDIM + 2 + DDIM + G, 256, 0, stream>>>(
      x, batch, W_in, b_in, W1, W2, WfT, W2T, bvec, Sb, counts, N, G);

  // 2) out = relu(Sb @ Wf + counts ⊗ bvec + b1) @ W2 + b2, one dispatch
  mlp_kernel<<<G / 16, 256, 0, stream>>>(Sb, WfT, W2T, bvec, b1, b2, counts,
                                         out);
}

// Round 14
// 185.926 us; speedup vs baseline: 6.5388x; 1.1287x over previous
//
#include <hip/hip_runtime.h>

#define DDIM 256
#define HDIM 512

typedef float f32x4 __attribute__((ext_vector_type(4)));
typedef short bf16x8 __attribute__((ext_vector_type(8)));

__device__ inline unsigned short f2bf(float f) {
  unsigned int u = __float_as_uint(f);
  u += 0x7fff + ((u >> 16) & 1);  // round-to-nearest-even
  return (unsigned short)(u >> 16);
}

// ---------------------------------------------------------------------------
// Fused main kernel. Weight-transform blocks FIRST so they overlap the
// HBM-bound segment stream:
//   blocks [0,514):      WfT[j][i] = (W_in@W1)[i][j] bf16; bvec = b_in@W1
//   blocks [514,770):    W2T[n][k] = W2[k][n] bf16
//   blocks [770,770+G):  segment g: binary-search rows, stream+sum x,
//                        store Sb[g] bf16 + counts[g]
// Nontemporal x loads are a measured +24 µs win (R13 A/B): x is one-pass
// streaming data; letting it allocate in L2/L3 evicts the hot weights.
// ---------------------------------------------------------------------------
__global__ __launch_bounds__(256) void fused_main_kernel(
    const float* __restrict__ x, const int* __restrict__ batch,
    const float* __restrict__ W_in, const float* __restrict__ b_in,
    const float* __restrict__ W1, const float* __restrict__ W2,
    unsigned short* __restrict__ WfT, unsigned short* __restrict__ W2T,
    float* __restrict__ bvec, unsigned short* __restrict__ Sb,
    float* __restrict__ counts, int N, int G) {
  const int b = blockIdx.x;

  if (b < 2 * DDIM + 2) {  // Wfused^T (bf16) and bvec
    __shared__ float vrow[DDIM];
    const bool is_b = (b >= 2 * DDIM);
    const int i = is_b ? 0 : (b >> 1);
    const int half = is_b ? (b - 2 * DDIM) : (b & 1);
    const float* src = is_b ? b_in : (W_in + (size_t)i * DDIM);
    vrow[threadIdx.x] = src[threadIdx.x];
    __syncthreads();

    const int j = half * 256 + threadIdx.x;
    float h = 0.f;
#pragma unroll 8
    for (int k = 0; k < DDIM; ++k) h += vrow[k] * W1[(size_t)k * HDIM + j];
    if (is_b) bvec[j] = h;
    else WfT[(size_t)j * DDIM + i] = f2bf(h);  // [N=512][K=256]
    return;
  }
  if (b < 2 * DDIM + 2 + DDIM) {  // W2^T (bf16)
    const int n = b - (2 * DDIM + 2);  // [N=256][K=512]
    for (int k = threadIdx.x; k < HDIM; k += 256)
      W2T[(size_t)n * HDIM + k] = f2bf(W2[(size_t)k * DDIM + n]);
    return;
  }

  // ---- segment-sum block ----
  const int g = b - (2 * DDIM + 2 + DDIM);
  __shared__ int se[2];
  __shared__ float red[3][DDIM];

  if (threadIdx.x < 2) {  // lower_bound(batch, g) and (g+1)
    const int target = g + threadIdx.x;
    int lo = 0, hi = N;
    while (lo < hi) {
      const int mid = (lo + hi) >> 1;
      if (batch[mid] < target) lo = mid + 1;
      else hi = mid;
    }
    se[threadIdx.x] = lo;
  }
  __syncthreads();
  const int start = se[0], end = se[1];

  const int w  = threadIdx.x >> 6;          // wave 0..3
  const int c4 = (threadIdx.x & 63) << 2;   // column base
  const float* xp = x + c4;

  f32x4 a0 = {0.f, 0.f, 0.f, 0.f};
  f32x4 a1 = {0.f, 0.f, 0.f, 0.f};
  f32x4 a2 = {0.f, 0.f, 0.f, 0.f};
  f32x4 a3 = {0.f, 0.f, 0.f, 0.f};

  int i = start + w;
  for (; i + 12 < end; i += 16) {
    const f32x4 v0 = __builtin_nontemporal_load(
        reinterpret_cast<const f32x4*>(xp + (size_t)i * DDIM));
    const f32x4 v1 = __builtin_nontemporal_load(
        reinterpret_cast<const f32x4*>(xp + (size_t)(i + 4) * DDIM));
    const f32x4 v2 = __builtin_nontemporal_load(
        reinterpret_cast<const f32x4*>(xp + (size_t)(i + 8) * DDIM));
    const f32x4 v3 = __builtin_nontemporal_load(
        reinterpret_cast<const f32x4*>(xp + (size_t)(i + 12) * DDIM));
    a0 += v0;
    a1 += v1;
    a2 += v2;
    a3 += v3;
  }
  for (; i < end; i += 4) {
    const f32x4 v0 = __builtin_nontemporal_load(
        reinterpret_cast<const f32x4*>(xp + (size_t)i * DDIM));
    a0 += v0;
  }
  a0 += a1;
  a2 += a3;
  a0 += a2;

  if (w != 0) *reinterpret_cast<f32x4*>(&red[w - 1][c4]) = a0;
  __syncthreads();
  if (w == 0) {
#pragma unroll
    for (int r = 0; r < 3; ++r) {
      a0 += *reinterpret_cast<const f32x4*>(&red[r][c4]);
    }
    ushort4 sv;
    sv.x = f2bf(a0.x);
    sv.y = f2bf(a0.y);
    sv.z = f2bf(a0.z);
    sv.w = f2bf(a0.w);
    *reinterpret_cast<ushort4*>(Sb + (size_t)g * DDIM + c4) = sv;
    if (threadIdx.x == 0) counts[g] = (float)(end - start);
  }
}

// ---------------------------------------------------------------------------
// Fused MLP: one block per 16-row slab. Phase 1: H = relu(Sb@Wf + cnt*bvec
// + b1) -> LDS as bf16 (XOR-swizzled both sides). Phase 2: out = H @ W2 + b2
// from LDS. MFMA fragment idiom as verified in R8: A row=lane&15, B col=
// lane&15, k=(lane>>4)*8+e; D col=lane&15, row=(lane>>4)*4+reg.
// ---------------------------------------------------------------------------
__global__ __launch_bounds__(256) void mlp_kernel(
    const unsigned short* __restrict__ Sb,
    const unsigned short* __restrict__ WfT,
    const unsigned short* __restrict__ W2T, const float* __restrict__ bvec,
    const float* __restrict__ b1, const float* __restrict__ b2,
    const float* __restrict__ counts, float* __restrict__ out) {
  __shared__ unsigned short Hs[16 * HDIM];  // 16 KB, swizzled layout
  const int tid = threadIdx.x;
  const int wid = tid >> 6, lane = tid & 63;
  const int l15 = lane & 15, lk8 = (lane >> 4) << 3;
  const int rbase = (lane >> 4) << 2;
  const int m0 = blockIdx.x * 16;

  // ---- Phase 1: H slab [16][512] ----
  const unsigned short* Ap = Sb + (size_t)(m0 + l15) * DDIM + lk8;
  const unsigned short* Bp = WfT + (size_t)(wid * 128 + l15) * DDIM + lk8;

  f32x4 acc[8] = {};
#pragma unroll
  for (int k0 = 0; k0 < DDIM; k0 += 32) {
    const bf16x8 a = *reinterpret_cast<const bf16x8*>(Ap + k0);
#pragma unroll
    for (int sj = 0; sj < 8; ++sj) {
      const bf16x8 bb =
          *reinterpret_cast<const bf16x8*>(Bp + (size_t)sj * 16 * DDIM + k0);
      acc[sj] = __builtin_amdgcn_mfma_f32_16x16x32_bf16(a, bb, acc[sj], 0, 0, 0);
    }
  }
  // epilogue -> LDS (swizzled bf16)
  char* hsb = (char*)Hs;
#pragma unroll
  for (int sj = 0; sj < 8; ++sj) {
    const int col = wid * 128 + sj * 16 + l15;
    const float vj = bvec[col];
    const float bj = b1[col];
#pragma unroll
    for (int r = 0; r < 4; ++r) {
      const int row = rbase + r;
      float v = acc[sj][r] + counts[m0 + row] * vj + bj;
      v = fmaxf(v, 0.f);
      const int byte = (row << 10) + (col << 1);
      *(unsigned short*)(hsb + (byte ^ ((row & 7) << 4))) = f2bf(v);
    }
  }
  __syncthreads();

  // ---- Phase 2: out slab [16][256] ----
  const unsigned short* B2p = W2T + (size_t)(wid * 64 + l15) * HDIM + lk8;
  f32x4 acc2[4] = {};
#pragma unroll
  for (int k0 = 0; k0 < HDIM; k0 += 32) {
    const int kb = (l15 << 10) + ((lk8 + k0) << 1);
    const bf16x8 a =
        *reinterpret_cast<const bf16x8*>(hsb + (kb ^ ((l15 & 7) << 4)));
#pragma unroll
    for (int sj = 0; sj < 4; ++sj) {
      const bf16x8 bb =
          *reinterpret_cast<const bf16x8*>(B2p + (size_t)sj * 16 * HDIM + k0);
      acc2[sj] = __builtin_amdgcn_mfma_f32_16x16x32_bf16(a, bb, acc2[sj], 0, 0, 0);
    }
  }
#pragma unroll
  for (int sj = 0; sj < 4; ++sj) {
    const int col = wid * 64 + sj * 16 + l15;
    const float bj = b2[col];
#pragma unroll
    for (int r = 0; r < 4; ++r) {
      const int row = m0 + rbase + r;
      out[(size_t)row * DDIM + col] = acc2[sj][r] + bj;
    }
  }
}

extern "C" void kernel_launch(void* const* d_in, const int* in_sizes, int n_in,
                              void* d_out, int out_size, void* d_ws,
                              size_t ws_size, hipStream_t stream) {
  const float* x     = (const float*)d_in[0];
  const int*   batch = (const int*)d_in[1];
  const float* W_in  = (const float*)d_in[2];
  const float* b_in  = (const float*)d_in[3];
  const float* W1    = (const float*)d_in[4];
  const float* b1    = (const float*)d_in[5];
  const float* W2    = (const float*)d_in[6];
  const float* b2    = (const float*)d_in[7];
  float* out = (float*)d_out;

  const int N = in_sizes[1];       // 1,000,000 rows
  const int G = out_size / DDIM;   // 4096 segments

  // Workspace layout (regions naturally aligned):
  char* wsb = (char*)d_ws;
  size_t off = 0;
  unsigned short* WfT = (unsigned short*)(wsb + off);  off += (size_t)HDIM * DDIM * 2;
  unsigned short* W2T = (unsigned short*)(wsb + off);  off += (size_t)DDIM * HDIM * 2;
  float* bvec   = (float*)(wsb + off);                 off += (size_t)HDIM * 4;
  float* counts = (float*)(wsb + off);                 off += (size_t)G * 4;
  unsigned short* Sb = (unsigned short*)(wsb + off);

  // 1) Weight transforms (first blocks, overlap the segment stream) + segsum
  fused_main_kernel<<<2 * DDIM + 2 + DDIM + G, 256, 0, stream>>>(
      x, batch, W_in, b_in, W1, W2, WfT, W2T, bvec, Sb, counts, N, G);

  // 2) out = relu(Sb @ Wf + counts ⊗ bvec + b1) @ W2 + b2, one dispatch
  mlp_kernel<<<G / 16, 256, 0, stream>>>(Sb, WfT, W2T, bvec, b1, b2, counts,
                                         out);
}